// Round 21
// baseline (23653.418 us; speedup 1.0000x reference)
//
#include <hip/hip_runtime.h>
#include <hip/hip_fp16.h>

#define B_ 256
#define T_ 512
#define H_ 2048
#define C_ 128
#define ASTR 520
#define BSTR2 1030
#define POLLCAP 200000

#define WS_H0 (0u)
#define WS_H1 (1u << 20)
#define WS_BT (2u << 20)

typedef _Float16 half8 __attribute__((ext_vector_type(8)));
typedef float floatx4 __attribute__((ext_vector_type(4)));

__device__ unsigned g_sync[8192];
__device__ _Float16 g_fb[2][8][32][H_];
__device__ _Float16 g_pk[2097152];

__device__ __forceinline__ half8 llc_load16(const _Float16* p) {
    union { unsigned long long u[2]; half8 h; } v;
    const unsigned long long* q = (const unsigned long long*)p;
    v.u[0] = __hip_atomic_load(q,     __ATOMIC_RELAXED, __HIP_MEMORY_SCOPE_AGENT);
    v.u[1] = __hip_atomic_load(q + 1, __ATOMIC_RELAXED, __HIP_MEMORY_SCOPE_AGENT);
    return v.h;
}

__device__ __forceinline__ int xcc_id() {
    int x;
    asm volatile("s_getreg_b32 %0, hwreg(HW_REG_XCC_ID)" : "=s"(x));
    return x & 7;
}

__device__ __forceinline__ void flag_inc(unsigned* p) {
    __hip_atomic_fetch_add(p, 1u, __ATOMIC_RELAXED, __HIP_MEMORY_SCOPE_AGENT);
}
__device__ __forceinline__ void flag_poll_ge(const unsigned* p, unsigned tgt) {
    int n = 0;
    while (__hip_atomic_load(p, __ATOMIC_RELAXED, __HIP_MEMORY_SCOPE_AGENT) < tgt
           && n < POLLCAP) { __builtin_amdgcn_s_sleep(2); ++n; }
}

__global__ void convert_whh(const float* __restrict__ W, _Float16* __restrict__ BT) {
    __shared__ float tile[64][65];
    const int kb = blockIdx.x * 64, nb = blockIdx.y * 64;
    const int tid = threadIdx.x;
    const int rc = tid & 63, rr = tid >> 6;
#pragma unroll
    for (int i = 0; i < 16; ++i)
        tile[i * 4 + rr][rc] = W[(size_t)(kb + i * 4 + rr) * H_ + nb + rc];
    __syncthreads();
    const int j = tid & 15, blk = (tid >> 4) & 1, nof = tid >> 5;
#pragma unroll
    for (int i = 0; i < 8; ++i) {
        int n = i * 8 + nof;
        _Float16 v0 = (_Float16)tile[blk * 32 + j][n];
        _Float16 v1 = (_Float16)tile[blk * 32 + 16 + j][n];
        unsigned pk = ((unsigned)__builtin_bit_cast(unsigned short, v1) << 16)
                    |  (unsigned)__builtin_bit_cast(unsigned short, v0);
        *(unsigned*)(BT + (size_t)(nb + n) * H_ + kb + blk * 32 + 2 * j) = pk;
    }
}

__global__ void pack_bt(const _Float16* __restrict__ BT) {
    int idx = blockIdx.x * blockDim.x + threadIdx.x;
    const int l  = idx & 63;
    const int u  = (idx >> 6) & 3;
    const int q  = (idx >> 8) & 7;
    const int w  = (idx >> 11) & 3;
    const int ns = idx >> 13;
    const int col = 64 * ns + 16 * w + (l & 15);
    const int kb  = 1024 + q * 128 + u * 32 + 8 * (l >> 4);
    *(half8*)(g_pk + (size_t)idx * 8) = *(const half8*)(BT + (size_t)col * H_ + kb);
}

__global__ void init_h(const int* __restrict__ x, const float* __restrict__ W_hx,
                       const float* __restrict__ b_h, char* __restrict__ ws) {
    int idx = blockIdx.x * blockDim.x + threadIdx.x;
    if (idx < 8192) g_sync[idx] = 0;
    _Float16* h0 = (_Float16*)(ws + WS_H0);
    int b = idx >> 11, s = idx & (H_ - 1);
    int j = (s & ~31) + ((s & 31) >> 1) + ((s & 1) << 4);
    int xv = x[b * T_];
    h0[idx] = (_Float16)tanhf(W_hx[(size_t)xv * H_ + j] + b_h[j]);
}

#define VWAIT(n)                                                            \
    asm volatile("s_waitcnt vmcnt(" #n ")" ::: "memory");                   \
    __builtin_amdgcn_sched_barrier(0);

#define ALD(BL, BH, q) {                                                    \
    const _Float16* _aL = apL + (q) * 128;                                  \
    const _Float16* _aH = apH + (q) * 128;                                  \
    _Pragma("unroll") for (int u = 0; u < 4; ++u)                           \
        asm volatile("global_load_dwordx4 %0, %1, off offset:%2 sc0"        \
                     : "=v"(BL[u]) : "v"(_aL), "i"(u * 64));                \
    _Pragma("unroll") for (int u = 0; u < 4; ++u)                           \
        asm volatile("global_load_dwordx4 %0, %1, off offset:%2 sc0"        \
                     : "=v"(BH[u]) : "v"(_aH), "i"(u * 64)); }

#define CP_LDS(BL, BH, q)                                                   \
    _Pragma("unroll") for (int u = 0; u < 4; ++u) {                         \
        half8 bv = *(const half8*)(bsp + (q) * 128 + u * 32);               \
        acc0 = __builtin_amdgcn_mfma_f32_16x16x32_f16(BL[u], bv, acc0, 0, 0, 0); \
        acc1 = __builtin_amdgcn_mfma_f32_16x16x32_f16(BH[u], bv, acc1, 0, 0, 0); \
    }

#define CP_BREG(BL, BH, qp)                                                 \
    _Pragma("unroll") for (int u = 0; u < 4; ++u) {                         \
        acc0 = __builtin_amdgcn_mfma_f32_16x16x32_f16(BL[u], breg[(qp) * 4 + u], acc0, 0, 0, 0); \
        acc1 = __builtin_amdgcn_mfma_f32_16x16x32_f16(BH[u], breg[(qp) * 4 + u], acc1, 0, 0, 0); \
    }

// shared prologue for ablated fast-path variants (no census, no flags)
#define ABL_PROLOGUE                                                        \
    _Float16* h0 = (_Float16*)(ws + WS_H0);                                 \
    const _Float16* BT = (const _Float16*)(ws + WS_BT);                     \
    const int tid = threadIdx.x;                                            \
    const int myxcd = xcc_id();                                             \
    const int ns = blockIdx.x & 31;                                         \
    const int w   = tid >> 6;                                               \
    const int l   = tid & 63;                                               \
    const int l15 = l & 15;                                                 \
    const int kl  = (l >> 4) << 3;                                          \
    _Float16* bsf = lds;                                                    \
    {                                                                       \
        const int c = tid >> 2, kseg = (tid & 3) * 256;                     \
        const _Float16* src = BT + (size_t)(ns * 64 + c) * H_ + kseg;       \
        _Float16* dst = bsf + c * BSTR2 + kseg;                             \
        _Pragma("unroll")                                                   \
        for (int i = 0; i < 32; ++i)                                        \
            *(half8*)(dst + i * 8) = *(const half8*)(src + i * 8);          \
    }                                                                       \
    {                                                                       \
        const _Float16* src = h0 + (size_t)(32 * myxcd + ns) * H_ + tid * 8;\
        *(half8*)(&g_fb[0][myxcd][ns][tid * 8]) = *(const half8*)(src);     \
    }                                                                       \
    const _Float16* pkp = g_pk + (size_t)(ns * 4 + w) * 16384 + l * 8;      \
    half8 breg[32];                                                         \
    _Pragma("unroll")                                                       \
    for (int q = 0; q < 8; ++q)                                             \
        _Pragma("unroll")                                                   \
        for (int u = 0; u < 4; ++u)                                         \
            breg[q * 4 + u] = *(const half8*)(pkp + q * 2048 + u * 512);    \
    __syncthreads();                                                        \
    const int r0l = (l >> 4) << 2;                                          \
    const int c0  = 64 * ns + 16 * w + l15;                                 \
    const float bh = b_h[c0];                                               \
    const _Float16* bsp = bsf + (16 * w + l15) * BSTR2 + kl;                \
    const int blk32 = 2 * ns + (w >> 1);                                    \
    const int selem = blk32 * 32 + ((w & 1) ? (2 * l15 + 1) : (2 * l15));

#define ABL_GATHERS                                                         \
    int   xv[8];                                                            \
    float wx[8];                                                            \
    _Pragma("unroll")                                                       \
    for (int jj = 0; jj < 4; ++jj) {                                        \
        xv[jj]     = x[(32 * myxcd + r0l + jj) * T_ + t];                   \
        xv[4 + jj] = x[(32 * myxcd + 16 + r0l + jj) * T_ + t];              \
    }                                                                       \
    _Pragma("unroll")                                                       \
    for (int jj = 0; jj < 8; ++jj)                                          \
        wx[jj] = W_hx[(size_t)xv[jj] * H_ + c0];                            \
    asm volatile("" ::: "memory");

#define ABL_PIPELINE                                                        \
    floatx4 acc0 = {0.f, 0.f, 0.f, 0.f}, acc1 = {0.f, 0.f, 0.f, 0.f};      \
    half8 XL[4], XH[4], YL[4], YH[4], ZL[4], ZH[4];                         \
    ALD(XL, XH, 0); ALD(YL, YH, 1);                                         \
    VWAIT(8);  ALD(ZL, ZH, 2);  CP_LDS(XL, XH, 0);                          \
    VWAIT(8);  ALD(XL, XH, 3);  CP_LDS(YL, YH, 1);                          \
    VWAIT(8);  ALD(YL, YH, 4);  CP_LDS(ZL, ZH, 2);                          \
    VWAIT(8);  ALD(ZL, ZH, 5);  CP_LDS(XL, XH, 3);                          \
    VWAIT(8);  ALD(XL, XH, 6);  CP_LDS(YL, YH, 4);                          \
    VWAIT(8);  ALD(YL, YH, 7);  CP_LDS(ZL, ZH, 5);                          \
    VWAIT(8);  ALD(ZL, ZH, 8);  CP_LDS(XL, XH, 6);                          \
    VWAIT(8);  ALD(XL, XH, 9);  CP_LDS(YL, YH, 7);                          \
    VWAIT(8);  ALD(YL, YH, 10); CP_BREG(ZL, ZH, 0);                         \
    VWAIT(8);  ALD(ZL, ZH, 11); CP_BREG(XL, XH, 1);                         \
    VWAIT(8);  ALD(XL, XH, 12); CP_BREG(YL, YH, 2);                         \
    VWAIT(8);  ALD(YL, YH, 13); CP_BREG(ZL, ZH, 3);                         \
    VWAIT(8);  ALD(ZL, ZH, 14); CP_BREG(XL, XH, 4);                         \
    VWAIT(8);  ALD(XL, XH, 15); CP_BREG(YL, YH, 5);                         \
    VWAIT(8);                   CP_BREG(ZL, ZH, 6);                         \
    VWAIT(0);                   CP_BREG(XL, XH, 7);

// ================= ABLATION VARIANTS (timing-only; results pinned) =================

// v_sync: census + gate + flag_inc + barriers ONLY (needs init_h-cleaned g_sync)
__global__ __launch_bounds__(256, 1)
void rnn_v_sync(char* __restrict__ ws, const int* __restrict__ x,
                const float* __restrict__ W_hx, const float* __restrict__ b_h) {
    extern __shared__ _Float16 lds[];
    __shared__ int s_wslot;
    unsigned* census = g_sync;
    const int tid = threadIdx.x;
    const int myxcd = xcc_id();
    if (tid == 0) {
        unsigned prev = __hip_atomic_fetch_add(&census[myxcd], 1u, __ATOMIC_RELAXED,
                                               __HIP_MEMORY_SCOPE_AGENT);
        __hip_atomic_fetch_add(&census[8], 1u, __ATOMIC_RELAXED, __HIP_MEMORY_SCOPE_AGENT);
        int p = 0;
        while (__hip_atomic_load(&census[8], __ATOMIC_RELAXED, __HIP_MEMORY_SCOPE_AGENT)
                   < 256u && p < POLLCAP) { __builtin_amdgcn_s_sleep(2); ++p; }
        s_wslot = (int)prev;
    }
    __syncthreads();
    (void)s_wslot;
    unsigned* scnt = &g_sync[32 + myxcd * 32];
    if (tid == 0) flag_inc(scnt);
    for (int t = 1; t < T_; ++t) {
        if (tid == 0) flag_poll_ge(scnt, 32u * (unsigned)t);
        __syncthreads();
        __syncthreads();
        if (tid == 0) flag_inc(scnt);
    }
}

// v_load: gathers + full A-pipeline + MFMA + tanh; NO publish, NO gate
__global__ __launch_bounds__(256, 1)
void rnn_v_load(char* __restrict__ ws, const int* __restrict__ x,
                const float* __restrict__ W_hx, const float* __restrict__ b_h) {
    extern __shared__ _Float16 lds[];
    ABL_PROLOGUE
    for (int t = 1; t < T_; ++t) {
        ABL_GATHERS
        const _Float16* fbp = &g_fb[(t - 1) & 1][myxcd][0][0];
        const _Float16* apL = fbp + (size_t)l15 * H_ + kl;
        const _Float16* apH = fbp + (size_t)(16 + l15) * H_ + kl;
        ABL_PIPELINE
#pragma unroll
        for (int jj = 0; jj < 4; ++jj) {
            float zL = acc0[jj] + wx[jj]     + bh;
            float zH = acc1[jj] + wx[4 + jj] + bh;
            _Float16 pL = (_Float16)tanhf(zL);
            _Float16 pH = (_Float16)tanhf(zH);
            asm volatile("" :: "v"((float)pL), "v"((float)pH));   // pin, no store
        }
        __syncthreads();
        __syncthreads();
    }
    (void)selem;
}

// v_nogate: full loop WITH publish, WITHOUT flag poll/inc
__global__ __launch_bounds__(256, 1)
void rnn_v_nogate(char* __restrict__ ws, const int* __restrict__ x,
                  const float* __restrict__ W_hx, const float* __restrict__ b_h) {
    extern __shared__ _Float16 lds[];
    ABL_PROLOGUE
    for (int t = 1; t < T_; ++t) {
        ABL_GATHERS
        const _Float16* fbp = &g_fb[(t - 1) & 1][myxcd][0][0];
        const _Float16* apL = fbp + (size_t)l15 * H_ + kl;
        const _Float16* apH = fbp + (size_t)(16 + l15) * H_ + kl;
        ABL_PIPELINE
        _Float16* fbn = &g_fb[t & 1][myxcd][0][0];
#pragma unroll
        for (int jj = 0; jj < 4; ++jj) {
            float zL = acc0[jj] + wx[jj]     + bh;
            float zH = acc1[jj] + wx[4 + jj] + bh;
            fbn[(size_t)(r0l + jj) * H_ + selem]      = (_Float16)tanhf(zL);
            fbn[(size_t)(16 + r0l + jj) * H_ + selem] = (_Float16)tanhf(zH);
        }
        __syncthreads();
        __syncthreads();
    }
}

// ================= REAL KERNEL (r20 verbatim) =================
__global__ __launch_bounds__(256, 1)
void rnn_steps(char* __restrict__ ws, const int* __restrict__ x,
               const float* __restrict__ W_hx, const float* __restrict__ b_h) {
    extern __shared__ _Float16 lds[];
    __shared__ int s_fast, s_wslot;
    _Float16* h0 = (_Float16*)(ws + WS_H0);
    _Float16* h1 = (_Float16*)(ws + WS_H1);
    const _Float16* BT = (const _Float16*)(ws + WS_BT);
    unsigned* census = g_sync;
    unsigned* gflags = g_sync + 4384;

    const int bid = blockIdx.x;
    const int tid = threadIdx.x;
    const int myxcd = xcc_id();

    if (tid == 0) {
        unsigned prev = __hip_atomic_fetch_add(&census[myxcd], 1u, __ATOMIC_RELAXED,
                                               __HIP_MEMORY_SCOPE_AGENT);
        __hip_atomic_fetch_add(&census[8], 1u, __ATOMIC_RELAXED, __HIP_MEMORY_SCOPE_AGENT);
        int p = 0;
        while (__hip_atomic_load(&census[8], __ATOMIC_RELAXED, __HIP_MEMORY_SCOPE_AGENT)
                   < 256u && p < POLLCAP) { __builtin_amdgcn_s_sleep(2); ++p; }
        int ok = (p < POLLCAP);
        if (ok)
            for (int i = 0; i < 8; ++i)
                if (__hip_atomic_load(&census[i], __ATOMIC_RELAXED, __HIP_MEMORY_SCOPE_AGENT)
                        != 32u) { ok = 0; break; }
        s_fast = ok; s_wslot = (int)prev;
    }
    __syncthreads();
    const bool fast = (s_fast != 0);
    const int wslot = s_wslot;

    const int w   = tid >> 6;
    const int l   = tid & 63;
    const int l15 = l & 15;
    const int kl  = (l >> 4) << 3;

    if (fast) {
        const int ns = wslot;
        _Float16* bsf = lds;
        unsigned* scnt = &g_sync[32 + myxcd * 32];
        {
            const int c = tid >> 2, kseg = (tid & 3) * 256;
            const _Float16* src = BT + (size_t)(ns * 64 + c) * H_ + kseg;
            _Float16* dst = bsf + c * BSTR2 + kseg;
#pragma unroll
            for (int i = 0; i < 32; ++i)
                *(half8*)(dst + i * 8) = *(const half8*)(src + i * 8);
        }
        {
            const _Float16* src = h0 + (size_t)(32 * myxcd + ns) * H_ + tid * 8;
            *(half8*)(&g_fb[0][myxcd][ns][tid * 8]) = *(const half8*)(src);
        }
        const _Float16* pkp = g_pk + (size_t)(ns * 4 + w) * 16384 + l * 8;
        half8 breg[32];
#pragma unroll
        for (int q = 0; q < 8; ++q)
#pragma unroll
            for (int u = 0; u < 4; ++u)
                breg[q * 4 + u] = *(const half8*)(pkp + q * 2048 + u * 512);
        __syncthreads();
        if (tid == 0) flag_inc(scnt);

        const int r0l = (l >> 4) << 2;
        const int c0  = 64 * ns + 16 * w + l15;
        const float bh = b_h[c0];
        const _Float16* bsp = bsf + (16 * w + l15) * BSTR2 + kl;
        const int blk32 = 2 * ns + (w >> 1);
        const int selem = blk32 * 32 + ((w & 1) ? (2 * l15 + 1) : (2 * l15));

        for (int t = 1; t < T_; ++t) {
            if (tid == 0) flag_poll_ge(scnt, 32u * (unsigned)t);
            __syncthreads();

            int   xv[8];
            float wx[8];
#pragma unroll
            for (int jj = 0; jj < 4; ++jj) {
                xv[jj]     = x[(32 * myxcd + r0l + jj) * T_ + t];
                xv[4 + jj] = x[(32 * myxcd + 16 + r0l + jj) * T_ + t];
            }
#pragma unroll
            for (int jj = 0; jj < 8; ++jj)
                wx[jj] = W_hx[(size_t)xv[jj] * H_ + c0];
            asm volatile("" ::: "memory");

            const _Float16* fbp = &g_fb[(t - 1) & 1][myxcd][0][0];
            const _Float16* apL = fbp + (size_t)l15 * H_ + kl;
            const _Float16* apH = fbp + (size_t)(16 + l15) * H_ + kl;
            floatx4 acc0 = {0.f, 0.f, 0.f, 0.f}, acc1 = {0.f, 0.f, 0.f, 0.f};
            half8 XL[4], XH[4], YL[4], YH[4], ZL[4], ZH[4];

            ALD(XL, XH, 0); ALD(YL, YH, 1);
            VWAIT(8);  ALD(ZL, ZH, 2);  CP_LDS(XL, XH, 0);
            VWAIT(8);  ALD(XL, XH, 3);  CP_LDS(YL, YH, 1);
            VWAIT(8);  ALD(YL, YH, 4);  CP_LDS(ZL, ZH, 2);
            VWAIT(8);  ALD(ZL, ZH, 5);  CP_LDS(XL, XH, 3);
            VWAIT(8);  ALD(XL, XH, 6);  CP_LDS(YL, YH, 4);
            VWAIT(8);  ALD(YL, YH, 7);  CP_LDS(ZL, ZH, 5);
            VWAIT(8);  ALD(ZL, ZH, 8);  CP_LDS(XL, XH, 6);
            VWAIT(8);  ALD(XL, XH, 9);  CP_LDS(YL, YH, 7);
            VWAIT(8);  ALD(YL, YH, 10); CP_BREG(ZL, ZH, 0);
            VWAIT(8);  ALD(ZL, ZH, 11); CP_BREG(XL, XH, 1);
            VWAIT(8);  ALD(XL, XH, 12); CP_BREG(YL, YH, 2);
            VWAIT(8);  ALD(YL, YH, 13); CP_BREG(ZL, ZH, 3);
            VWAIT(8);  ALD(ZL, ZH, 14); CP_BREG(XL, XH, 4);
            VWAIT(8);  ALD(XL, XH, 15); CP_BREG(YL, YH, 5);
            VWAIT(8);                   CP_BREG(ZL, ZH, 6);
            VWAIT(0);                   CP_BREG(XL, XH, 7);

            _Float16* fbn = &g_fb[t & 1][myxcd][0][0];
#pragma unroll
            for (int jj = 0; jj < 4; ++jj) {
                float zL = acc0[jj] + wx[jj]     + bh;
                float zH = acc1[jj] + wx[4 + jj] + bh;
                _Float16 pL = (_Float16)tanhf(zL);
                _Float16 pH = (_Float16)tanhf(zH);
                fbn[(size_t)(r0l + jj) * H_ + selem]      = pL;
                fbn[(size_t)(16 + r0l + jj) * H_ + selem] = pH;
                if (t == T_ - 1) {
                    h1[(size_t)(32 * myxcd + r0l + jj) * H_ + selem]      = pL;
                    h1[(size_t)(32 * myxcd + 16 + r0l + jj) * H_ + selem] = pH;
                }
            }
            __syncthreads();
            if (tid == 0) flag_inc(scnt);
        }
        return;
    }

    // ---------------- FALLBACK: r12-proven IF$ path (verbatim) ----------------
    _Float16* Asl = lds;
    const int rb  = bid >> 4;
    const int cb  = bid & 15;
    const int nb  = cb * 128;
    const int cw  = nb + w * 32;
    const int rbr = rb * 16;
    const int srow = tid >> 4;
    const int skb  = (tid & 15) * 32;
    const int r0 = rbr + ((l >> 4) << 2);
    const int c0 = cw + l15;
    const float bh0 = b_h[c0], bh1 = b_h[c0 + 16];
    unsigned* myflag = &gflags[(rb * 16 + cb) * 4];

#define POLLF(qq) {                                                         \
    int guard = 0;                                                          \
    for (;;) {                                                              \
        unsigned fvv = need;                                                \
        if (l < 4) fvv = __hip_atomic_load(&gflags[(rb * 16 + (qq) * 4 + l) * 4], \
                                           __ATOMIC_RELAXED, __HIP_MEMORY_SCOPE_AGENT); \
        if (__ballot(fvv >= need) == ~0ull) break;                          \
        if (++guard > POLLCAP) break;                                       \
        __builtin_amdgcn_s_sleep(2);                                        \
    } }
#define STAGE_LOAD(hb, qq, r) {                                             \
    const _Float16* sp = (hb) + (size_t)(rbr + srow) * H_ + (qq) * 512 + skb; \
    r[0] = llc_load16(sp);      r[1] = llc_load16(sp + 8);                  \
    r[2] = llc_load16(sp + 16); r[3] = llc_load16(sp + 24); }
#define STAGE_WRITE(buf, r) {                                               \
    _Float16* dp = Asl + (buf) * 16 * ASTR + srow * ASTR + skb;             \
    *(half8*)(dp)      = r[0]; *(half8*)(dp + 8)  = r[1];                   \
    *(half8*)(dp + 16) = r[2]; *(half8*)(dp + 24) = r[3]; }
#define COMPUTE(qq) {                                                       \
    const _Float16* ar  = Asl + ((qq) & 1) * 16 * ASTR + l15 * ASTR + kl;   \
    const _Float16* b0p = BT + (size_t)(cw + l15) * H_ + (qq) * 512 + kl;   \
    const _Float16* b1p = BT + (size_t)(cw + 16 + l15) * H_ + (qq) * 512 + kl; \
    _Pragma("unroll")                                                       \
    for (int i = 0; i < 16; ++i) {                                          \
        half8 a  = *(const half8*)(ar  + i * 32);                           \
        half8 b0 = *(const half8*)(b0p + i * 32);                           \
        half8 b1 = *(const half8*)(b1p + i * 32);                           \
        acc0 = __builtin_amdgcn_mfma_f32_16x16x32_f16(a, b0, acc0, 0, 0, 0);\
        acc1 = __builtin_amdgcn_mfma_f32_16x16x32_f16(a, b1, acc1, 0, 0, 0);\
    } }

    for (int t = 1; t < T_; ++t) {
        const _Float16* __restrict__ hc = (t & 1) ? h0 : h1;
        _Float16* __restrict__ hn       = (t & 1) ? h1 : h0;
        const unsigned need = (unsigned)(t - 1);

        int   xv[4];
        float wx0[4], wx1[4];
#pragma unroll
        for (int jj = 0; jj < 4; ++jj) xv[jj] = x[(r0 + jj) * T_ + t];
#pragma unroll
        for (int jj = 0; jj < 4; ++jj) {
            wx0[jj] = W_hx[(size_t)xv[jj] * H_ + c0];
            wx1[jj] = W_hx[(size_t)xv[jj] * H_ + c0 + 16];
        }

        floatx4 acc0 = {0.f, 0.f, 0.f, 0.f}, acc1 = {0.f, 0.f, 0.f, 0.f};
        POLLF(0);
        {
            half8 rA[4];
            STAGE_LOAD(hc, 0, rA);
            STAGE_WRITE(0, rA);
        }
        __syncthreads();
#pragma unroll
        for (int q = 0; q < 4; ++q) {
            half8 rN[4];
            if (q < 3) { POLLF(q + 1); STAGE_LOAD(hc, q + 1, rN); }
            COMPUTE(q);
            if (q < 3) {
                __syncthreads();
                STAGE_WRITE((q + 1) & 1, rN);
                __syncthreads();
            }
        }
        unsigned o[4];
#pragma unroll
        for (int jj = 0; jj < 4; ++jj) {
            float z0 = acc0[jj] + wx0[jj] + bh0;
            float z1 = acc1[jj] + wx1[jj] + bh1;
            _Float16 p0 = (_Float16)tanhf(z0), p1 = (_Float16)tanhf(z1);
            unsigned pv = ((unsigned)__builtin_bit_cast(unsigned short, p1) << 16)
                        |  (unsigned)__builtin_bit_cast(unsigned short, p0);
            unsigned* dstp = (unsigned*)(hn + (size_t)(r0 + jj) * H_ + cw + 2 * l15);
            o[jj] = __hip_atomic_exchange(dstp, pv, __ATOMIC_RELAXED,
                                          __HIP_MEMORY_SCOPE_AGENT);
        }
        asm volatile("" :: "v"(o[0]), "v"(o[1]), "v"(o[2]), "v"(o[3]));
        __syncthreads();
        if (tid == 0) {
            __builtin_amdgcn_fence(__ATOMIC_RELEASE, "workgroup");
            __hip_atomic_fetch_add(myflag, 1u, __ATOMIC_RELAXED, __HIP_MEMORY_SCOPE_AGENT);
        }
    }
}

__global__ void final_proj(const char* __restrict__ ws, const float* __restrict__ W_ph,
                           const float* __restrict__ b_p, float* __restrict__ out) {
    __shared__ float part[C_];
    const _Float16* h = (const _Float16*)(ws + WS_H1);
    const int b  = blockIdx.x;
    const int c  = threadIdx.x & (C_ - 1);
    const int hh = threadIdx.x >> 7;
    const int j0 = hh * (H_ / 2);
    float acc = 0.f;
#pragma unroll 4
    for (int s = j0; s < j0 + H_ / 2; ++s) {
        int k = (s & ~31) + ((s & 31) >> 1) + ((s & 1) << 4);
        acc = fmaf((float)h[(size_t)b * H_ + s], W_ph[k * C_ + c], acc);
    }
    if (hh) part[c] = acc;
    __syncthreads();
    if (!hh) out[b * C_ + c] = acc + part[c] + b_p[c];
}

extern "C" void kernel_launch(void* const* d_in, const int* in_sizes, int n_in,
                              void* d_out, int out_size, void* d_ws, size_t ws_size,
                              hipStream_t stream) {
    const int*   x    = (const int*)d_in[0];
    const float* W_hx = (const float*)d_in[1];
    const float* W_hh = (const float*)d_in[2];
    const float* W_ph = (const float*)d_in[3];
    const float* b_h  = (const float*)d_in[4];
    const float* b_p  = (const float*)d_in[5];
    float* out = (float*)d_out;
    char* ws = (char*)d_ws;

    convert_whh<<<dim3(H_ / 64, H_ / 64), 256, 0, stream>>>(W_hh, (_Float16*)(ws + WS_BT));
    pack_bt<<<1024, 256, 0, stream>>>((const _Float16*)(ws + WS_BT));

    const int smem = 64 * BSTR2 * 2;
    (void)hipFuncSetAttribute((const void*)rnn_steps,
                              hipFuncAttributeMaxDynamicSharedMemorySize, smem);
    (void)hipFuncSetAttribute((const void*)rnn_v_sync,
                              hipFuncAttributeMaxDynamicSharedMemorySize, smem);
    (void)hipFuncSetAttribute((const void*)rnn_v_load,
                              hipFuncAttributeMaxDynamicSharedMemorySize, smem);
    (void)hipFuncSetAttribute((const void*)rnn_v_nogate,
                              hipFuncAttributeMaxDynamicSharedMemorySize, smem);

    char* pws = ws;
    const int* px = x; const float* pwhx = W_hx; const float* pbh = b_h;
    void* args[] = {(void*)&pws, (void*)&px, (void*)&pwhx, (void*)&pbh};

    // --- ablation dispatches (timing-only; read their dur_us from rocprof) ---
    init_h<<<(B_ * H_) / 256, 256, 0, stream>>>(x, W_hx, b_h, ws);
    hipLaunchCooperativeKernel((void*)rnn_v_sync, dim3(256), dim3(256), args, smem, stream);
    rnn_v_load<<<dim3(256), dim3(256), smem, stream>>>(pws, px, pwhx, pbh);
    rnn_v_nogate<<<dim3(256), dim3(256), smem, stream>>>(pws, px, pwhx, pbh);

    // --- real run (validated output) ---
    init_h<<<(B_ * H_) / 256, 256, 0, stream>>>(x, W_hx, b_h, ws);
    hipError_t e = hipLaunchCooperativeKernel((void*)rnn_steps, dim3(256), dim3(256),
                                              args, smem, stream);
    if (e != hipSuccess) {
        rnn_steps<<<dim3(256), dim3(256), smem, stream>>>(pws, px, pwhx, pbh);
    }

    final_proj<<<B_, 256, 0, stream>>>(ws, W_ph, b_p, out);
}